// Round 2
// baseline (209.535 us; speedup 1.0000x reference)
//
#include <hip/hip_runtime.h>

#define NDOF 7
#define BLK 256
#define STAGE (BLK * NDOF)
#define CST_STRIDE 24   // floats per dof block in d_ws (16B aligned: 24*4=96)

// ---------- tiny vec3 ----------
struct V3 { float x, y, z; };
__device__ __forceinline__ V3 operator+(V3 a, V3 b) { return {a.x + b.x, a.y + b.y, a.z + b.z}; }
__device__ __forceinline__ V3 operator-(V3 a, V3 b) { return {a.x - b.x, a.y - b.y, a.z - b.z}; }
__device__ __forceinline__ V3 operator*(float s, V3 a) { return {s * a.x, s * a.y, s * a.z}; }
__device__ __forceinline__ V3 cross(V3 a, V3 b) {
    return {a.y * b.z - a.z * b.y, a.z * b.x - a.x * b.z, a.x * b.y - a.y * b.x};
}
__device__ __forceinline__ float dot(V3 a, V3 b) { return a.x * b.x + a.y * b.y + a.z * b.z; }

// ---------- prep: pack per-dof constants into d_ws ----------
// layout per dof d (stride 24 floats):
//  [0:9)  F columns: Fc0=(F00,F10,F20), Fc1=(F01,F11,F21), Fc2=(F02,F12,F22)
//  [9:12) p = trans_fix[1+d]
//  [12:18) Io6 = I00,I01,I02,I11,I12,I22  (inertia + m*(|c|^2 I - c c^T))
//  [18]   m
//  [19:22) mc = m*com
//  [22]   damping
__global__ void rnea_prep(const float* __restrict__ rot_fix,
                          const float* __restrict__ trans_fix,
                          const float* __restrict__ mass_g,
                          const float* __restrict__ com_g,
                          const float* __restrict__ inertia_g,
                          const float* __restrict__ damping_g,
                          float* __restrict__ cst) {
    const int d = threadIdx.x;
    if (d >= NDOF) return;
    float* o = cst + d * CST_STRIDE;
    const float* F = rot_fix + (1 + d) * 9;
#pragma unroll
    for (int j = 0; j < 3; j++)
#pragma unroll
        for (int i = 0; i < 3; i++) o[j * 3 + i] = F[i * 3 + j];  // column-major
#pragma unroll
    for (int i = 0; i < 3; i++) o[9 + i] = trans_fix[(1 + d) * 3 + i];
    const float m = mass_g[1 + d];
    const float c0 = com_g[(1 + d) * 3 + 0];
    const float c1 = com_g[(1 + d) * 3 + 1];
    const float c2 = com_g[(1 + d) * 3 + 2];
    const float* I = inertia_g + (1 + d) * 9;
    // skew(c) @ skew(c)^T = |c|^2 I - c c^T
    o[12] = I[0] + m * (c1 * c1 + c2 * c2);
    o[13] = I[1] - m * c0 * c1;
    o[14] = I[2] - m * c0 * c2;
    o[15] = I[4] + m * (c0 * c0 + c2 * c2);
    o[16] = I[5] - m * c1 * c2;
    o[17] = I[8] + m * (c0 * c0 + c1 * c1);
    o[18] = m;
    o[19] = m * c0;
    o[20] = m * c1;
    o[21] = m * c2;
    o[22] = damping_g[d];
    o[23] = 0.f;
}

// ---------- per-dof steps, axis known at compile time ----------
// AX: 0 = +z, 1 = +y, 2 = -y   (joint_axes is a literal in the reference)
template <int AX>
__device__ __forceinline__ void make_R(const float* __restrict__ C, float s, float c,
                                       V3& R0, V3& R1, V3& R2) {
    V3 Fc0{C[0], C[1], C[2]}, Fc1{C[3], C[4], C[5]}, Fc2{C[6], C[7], C[8]};
    if (AX == 0) {          // Rq_z cols: (c,s,0), (-s,c,0), (0,0,1)
        R0 = c * Fc0 + s * Fc1;
        R1 = c * Fc1 - s * Fc0;
        R2 = Fc2;
    } else if (AX == 1) {   // Rq_y cols: (c,0,-s), (0,1,0), (s,0,c)
        R0 = c * Fc0 - s * Fc2;
        R1 = Fc1;
        R2 = s * Fc0 + c * Fc2;
    } else {                // Rq_-y cols: (c,0,s), (0,1,0), (-s,0,c)
        R0 = c * Fc0 + s * Fc2;
        R1 = Fc1;
        R2 = c * Fc2 - s * Fc0;
    }
}

template <int AX>
__device__ __forceinline__ void fwd_step(const float* __restrict__ C, float q, float qd,
                                         float qdd, V3& vl, V3& va, V3& al, V3& aa,
                                         float& s_sv, float& c_sv, V3& fl, V3& fa) {
    float s, c;
    __sincosf(q, &s, &c);
    s_sv = s;
    c_sv = c;
    V3 R0, R1, R2;
    make_R<AX>(C, s, c, R0, R1, R2);
    V3 p{C[9], C[10], C[11]};

    // Rt(vl) + cross(-Rt p, Rt va) == Rt(vl + va x p)   (rotation equivariance)
    V3 w1 = vl + cross(va, p);
    V3 w2 = al + cross(aa, p);
    V3 nvl{dot(R0, w1), dot(R1, w1), dot(R2, w1)};
    V3 nva{dot(R0, va), dot(R1, va), dot(R2, va)};
    V3 nal{dot(R0, w2), dot(R1, w2), dot(R2, w2)};
    V3 naa{dot(R0, aa), dot(R1, aa), dot(R2, aa)};

    if (AX == 0) {          // jv=(0,0,qd), ja=(0,0,qdd); cross(v,jv)=(v.y*qd,-v.x*qd,0)
        va = {nva.x, nva.y, nva.z + qd};
        aa = {naa.x + va.y * qd, naa.y - va.x * qd, naa.z + qdd};
        vl = nvl;
        al = {nal.x + vl.y * qd, nal.y - vl.x * qd, nal.z};
    } else if (AX == 1) {   // jv=(0,qd,0); cross(v,jv)=(-v.z*qd,0,v.x*qd)
        va = {nva.x, nva.y + qd, nva.z};
        aa = {naa.x - va.z * qd, naa.y + qdd, naa.z + va.x * qd};
        vl = nvl;
        al = {nal.x - vl.z * qd, nal.y, nal.z + vl.x * qd};
    } else {                // jv=(0,-qd,0); cross(v,jv)=(v.z*qd,0,-v.x*qd)
        va = {nva.x, nva.y - qd, nva.z};
        aa = {naa.x + va.z * qd, naa.y - qdd, naa.z - va.x * qd};
        vl = nvl;
        al = {nal.x + vl.z * qd, nal.y, nal.z - vl.x * qd};
    }

    const float I00 = C[12], I01 = C[13], I02 = C[14], I11 = C[15], I12 = C[16], I22 = C[17];
    const float m = C[18];
    V3 mc{C[19], C[20], C[21]};
    V3 Ial = m * al + cross(aa, mc);
    V3 Iaa = V3{I00 * aa.x + I01 * aa.y + I02 * aa.z,
                I01 * aa.x + I11 * aa.y + I12 * aa.z,
                I02 * aa.x + I12 * aa.y + I22 * aa.z} + cross(mc, al);
    V3 Ivl = m * vl + cross(va, mc);
    V3 Iva = V3{I00 * va.x + I01 * va.y + I02 * va.z,
                I01 * va.x + I11 * va.y + I12 * va.z,
                I02 * va.x + I12 * va.y + I22 * va.z} + cross(mc, vl);
    fl = Ial + cross(va, Ivl);
    fa = Iaa + cross(va, Iva) + cross(vl, Ivl);
}

template <int AX>
__device__ __forceinline__ float bwd_step(const float* __restrict__ C, float s, float c,
                                          V3 fl, V3 fa, V3& cl, V3& ca) {
    V3 tl = fl + cl;
    V3 ta = fa + ca;
    float tau;
    if (AX == 0) tau = ta.z;
    else if (AX == 1) tau = ta.y;
    else tau = -ta.y;

    V3 R0, R1, R2;
    make_R<AX>(C, s, c, R0, R1, R2);
    V3 p{C[9], C[10], C[11]};
    V3 nl = tl.x * R0 + tl.y * R1 + tl.z * R2;               // R @ tl (cols)
    V3 na = ta.x * R0 + ta.y * R1 + ta.z * R2 + cross(p, nl);
    cl = nl;
    ca = na;
    return tau;
}

// ---------- main kernel ----------
__global__ __launch_bounds__(BLK, 3) void rnea_main(
    const float* __restrict__ q_g, const float* __restrict__ qd_g,
    const float* __restrict__ qdd_g, const float* __restrict__ cst,
    float* __restrict__ out, int n_elem) {
    __shared__ float sQ[STAGE], sQd[STAGE], sQdd[STAGE];
    const int t = threadIdx.x;
    const int base = blockIdx.x * STAGE;
#pragma unroll
    for (int i = t; i < STAGE; i += BLK) {
        const int g = base + i;
        const bool ok = g < n_elem;
        sQ[i] = ok ? q_g[g] : 0.f;
        sQd[i] = ok ? qd_g[g] : 0.f;
        sQdd[i] = ok ? qdd_g[g] : 0.f;
    }
    __syncthreads();

    const int o = t * NDOF;
    V3 vl{0.f, 0.f, 0.f}, va{0.f, 0.f, 0.f}, al{0.f, 0.f, 9.81f}, aa{0.f, 0.f, 0.f};
    float ss[NDOF], cc[NDOF];
    V3 fl[NDOF], fa[NDOF];

    // axis sequence: z, y, z, -y, z, y, z
    fwd_step<0>(cst + 0 * CST_STRIDE, sQ[o + 0], sQd[o + 0], sQdd[o + 0], vl, va, al, aa, ss[0], cc[0], fl[0], fa[0]);
    fwd_step<1>(cst + 1 * CST_STRIDE, sQ[o + 1], sQd[o + 1], sQdd[o + 1], vl, va, al, aa, ss[1], cc[1], fl[1], fa[1]);
    fwd_step<0>(cst + 2 * CST_STRIDE, sQ[o + 2], sQd[o + 2], sQdd[o + 2], vl, va, al, aa, ss[2], cc[2], fl[2], fa[2]);
    fwd_step<2>(cst + 3 * CST_STRIDE, sQ[o + 3], sQd[o + 3], sQdd[o + 3], vl, va, al, aa, ss[3], cc[3], fl[3], fa[3]);
    fwd_step<0>(cst + 4 * CST_STRIDE, sQ[o + 4], sQd[o + 4], sQdd[o + 4], vl, va, al, aa, ss[4], cc[4], fl[4], fa[4]);
    fwd_step<1>(cst + 5 * CST_STRIDE, sQ[o + 5], sQd[o + 5], sQdd[o + 5], vl, va, al, aa, ss[5], cc[5], fl[5], fa[5]);
    fwd_step<0>(cst + 6 * CST_STRIDE, sQ[o + 6], sQd[o + 6], sQdd[o + 6], vl, va, al, aa, ss[6], cc[6], fl[6], fa[6]);

    V3 cl{0.f, 0.f, 0.f}, ca{0.f, 0.f, 0.f};
    float tau[NDOF];
    tau[6] = bwd_step<0>(cst + 6 * CST_STRIDE, ss[6], cc[6], fl[6], fa[6], cl, ca);
    tau[5] = bwd_step<1>(cst + 5 * CST_STRIDE, ss[5], cc[5], fl[5], fa[5], cl, ca);
    tau[4] = bwd_step<0>(cst + 4 * CST_STRIDE, ss[4], cc[4], fl[4], fa[4], cl, ca);
    tau[3] = bwd_step<2>(cst + 3 * CST_STRIDE, ss[3], cc[3], fl[3], fa[3], cl, ca);
    tau[2] = bwd_step<0>(cst + 2 * CST_STRIDE, ss[2], cc[2], fl[2], fa[2], cl, ca);
    tau[1] = bwd_step<1>(cst + 1 * CST_STRIDE, ss[1], cc[1], fl[1], fa[1], cl, ca);
    tau[0] = bwd_step<0>(cst + 0 * CST_STRIDE, ss[0], cc[0], fl[0], fa[0], cl, ca);

    __syncthreads();
#pragma unroll
    for (int d = 0; d < NDOF; d++)
        sQ[o + d] = tau[d] + cst[d * CST_STRIDE + 22] * sQd[o + d];
    __syncthreads();
#pragma unroll
    for (int i = t; i < STAGE; i += BLK) {
        const int g = base + i;
        if (g < n_elem) out[g] = sQ[i];
    }
}

extern "C" void kernel_launch(void* const* d_in, const int* in_sizes, int n_in,
                              void* d_out, int out_size, void* d_ws, size_t ws_size,
                              hipStream_t stream) {
    const float* q = (const float*)d_in[0];
    const float* qd = (const float*)d_in[1];
    const float* qdd = (const float*)d_in[2];
    const float* rot_fix = (const float*)d_in[3];
    const float* trans_fix = (const float*)d_in[4];
    // d_in[5] = joint_axes: compile-time constant in the reference (z,y,z,-y,z,y,z)
    const float* mass = (const float*)d_in[6];
    const float* com = (const float*)d_in[7];
    const float* inertia = (const float*)d_in[8];
    const float* damping = (const float*)d_in[9];
    float* out = (float*)d_out;
    float* cst = (float*)d_ws;  // 7*24*4 = 672 B

    const int n_elem = in_sizes[0];  // B * 7
    const int B = n_elem / NDOF;
    const int grid = (B + BLK - 1) / BLK;

    rnea_prep<<<1, 64, 0, stream>>>(rot_fix, trans_fix, mass, com, inertia, damping, cst);
    rnea_main<<<grid, BLK, 0, stream>>>(q, qd, qdd, cst, out, n_elem);
}

// Round 3
// 160.299 us; speedup vs baseline: 1.3072x; 1.3072x over previous
//
#include <hip/hip_runtime.h>

#define NDOF 7
#define BLK 256
#define STAGE (BLK * NDOF)
#define CST_STRIDE 24   // floats per dof block in d_ws

// ---------- tiny vec3 ----------
struct V3 { float x, y, z; };
__device__ __forceinline__ V3 operator+(V3 a, V3 b) { return {a.x + b.x, a.y + b.y, a.z + b.z}; }
__device__ __forceinline__ V3 operator-(V3 a, V3 b) { return {a.x - b.x, a.y - b.y, a.z - b.z}; }
__device__ __forceinline__ V3 operator*(float s, V3 a) { return {s * a.x, s * a.y, s * a.z}; }
__device__ __forceinline__ V3 cross(V3 a, V3 b) {
    return {a.y * b.z - a.z * b.y, a.z * b.x - a.x * b.z, a.x * b.y - a.y * b.x};
}
__device__ __forceinline__ float dot(V3 a, V3 b) { return a.x * b.x + a.y * b.y + a.z * b.z; }

// ---------- prep: pack per-dof constants into d_ws ----------
// layout per dof d (stride 24 floats):
//  [0:9)  F columns: Fc0=(F00,F10,F20), Fc1=(F01,F11,F21), Fc2=(F02,F12,F22)
//  [9:12) p = trans_fix[1+d]
//  [12:18) Io6 = I00,I01,I02,I11,I12,I22  (inertia + m*(|c|^2 I - c c^T))
//  [18]   m
//  [19:22) mc = m*com
//  [22]   damping
__global__ void rnea_prep(const float* __restrict__ rot_fix,
                          const float* __restrict__ trans_fix,
                          const float* __restrict__ mass_g,
                          const float* __restrict__ com_g,
                          const float* __restrict__ inertia_g,
                          const float* __restrict__ damping_g,
                          float* __restrict__ cst) {
    const int d = threadIdx.x;
    if (d >= NDOF) return;
    float* o = cst + d * CST_STRIDE;
    const float* F = rot_fix + (1 + d) * 9;
#pragma unroll
    for (int j = 0; j < 3; j++)
#pragma unroll
        for (int i = 0; i < 3; i++) o[j * 3 + i] = F[i * 3 + j];  // column-major
#pragma unroll
    for (int i = 0; i < 3; i++) o[9 + i] = trans_fix[(1 + d) * 3 + i];
    const float m = mass_g[1 + d];
    const float c0 = com_g[(1 + d) * 3 + 0];
    const float c1 = com_g[(1 + d) * 3 + 1];
    const float c2 = com_g[(1 + d) * 3 + 2];
    const float* I = inertia_g + (1 + d) * 9;
    // skew(c) @ skew(c)^T = |c|^2 I - c c^T
    o[12] = I[0] + m * (c1 * c1 + c2 * c2);
    o[13] = I[1] - m * c0 * c1;
    o[14] = I[2] - m * c0 * c2;
    o[15] = I[4] + m * (c0 * c0 + c2 * c2);
    o[16] = I[5] - m * c1 * c2;
    o[17] = I[8] + m * (c0 * c0 + c1 * c1);
    o[18] = m;
    o[19] = m * c0;
    o[20] = m * c1;
    o[21] = m * c2;
    o[22] = damping_g[d];
    o[23] = 0.f;
}

// ---------- per-dof steps, axis known at compile time ----------
// AX: 0 = +z, 1 = +y, 2 = -y   (joint_axes is a literal in the reference)
template <int AX>
__device__ __forceinline__ void make_R(const float* __restrict__ C, float s, float c,
                                       V3& R0, V3& R1, V3& R2) {
    V3 Fc0{C[0], C[1], C[2]}, Fc1{C[3], C[4], C[5]}, Fc2{C[6], C[7], C[8]};
    if (AX == 0) {          // Rq_z cols: (c,s,0), (-s,c,0), (0,0,1)
        R0 = c * Fc0 + s * Fc1;
        R1 = c * Fc1 - s * Fc0;
        R2 = Fc2;
    } else if (AX == 1) {   // Rq_y cols: (c,0,-s), (0,1,0), (s,0,c)
        R0 = c * Fc0 - s * Fc2;
        R1 = Fc1;
        R2 = s * Fc0 + c * Fc2;
    } else {                // Rq_-y cols: (c,0,s), (0,1,0), (-s,0,c)
        R0 = c * Fc0 + s * Fc2;
        R1 = Fc1;
        R2 = c * Fc2 - s * Fc0;
    }
}

template <int AX>
__device__ __forceinline__ void fwd_step(const float* __restrict__ C, float q, float qd,
                                         float qdd, V3& vl, V3& va, V3& al, V3& aa,
                                         float& s_sv, float& c_sv, V3& fl, V3& fa) {
    // NOTE: __sinf/__cosf only — the pointer-form __sincosf (__ocml_sincos_f32)
    // escapes an addrspace(5) pointer, defeats SROA, and put ~690 B/thread of
    // arrays into scratch in round 2 (WRITE_SIZE 14->256 MB, VGPR 184->84).
    const float s = __sinf(q);
    const float c = __cosf(q);
    s_sv = s;
    c_sv = c;
    V3 R0, R1, R2;
    make_R<AX>(C, s, c, R0, R1, R2);
    V3 p{C[9], C[10], C[11]};

    // Rt(vl) + cross(-Rt p, Rt va) == Rt(vl + va x p)   (rotation equivariance)
    V3 w1 = vl + cross(va, p);
    V3 w2 = al + cross(aa, p);
    V3 nvl{dot(R0, w1), dot(R1, w1), dot(R2, w1)};
    V3 nva{dot(R0, va), dot(R1, va), dot(R2, va)};
    V3 nal{dot(R0, w2), dot(R1, w2), dot(R2, w2)};
    V3 naa{dot(R0, aa), dot(R1, aa), dot(R2, aa)};

    if (AX == 0) {          // jv=(0,0,qd), ja=(0,0,qdd); cross(v,jv)=(v.y*qd,-v.x*qd,0)
        va = {nva.x, nva.y, nva.z + qd};
        aa = {naa.x + va.y * qd, naa.y - va.x * qd, naa.z + qdd};
        vl = nvl;
        al = {nal.x + vl.y * qd, nal.y - vl.x * qd, nal.z};
    } else if (AX == 1) {   // jv=(0,qd,0); cross(v,jv)=(-v.z*qd,0,v.x*qd)
        va = {nva.x, nva.y + qd, nva.z};
        aa = {naa.x - va.z * qd, naa.y + qdd, naa.z + va.x * qd};
        vl = nvl;
        al = {nal.x - vl.z * qd, nal.y, nal.z + vl.x * qd};
    } else {                // jv=(0,-qd,0); cross(v,jv)=(v.z*qd,0,-v.x*qd)
        va = {nva.x, nva.y - qd, nva.z};
        aa = {naa.x + va.z * qd, naa.y - qdd, naa.z - va.x * qd};
        vl = nvl;
        al = {nal.x + vl.z * qd, nal.y, nal.z - vl.x * qd};
    }

    const float I00 = C[12], I01 = C[13], I02 = C[14], I11 = C[15], I12 = C[16], I22 = C[17];
    const float m = C[18];
    V3 mc{C[19], C[20], C[21]};
    V3 Ial = m * al + cross(aa, mc);
    V3 Iaa = V3{I00 * aa.x + I01 * aa.y + I02 * aa.z,
                I01 * aa.x + I11 * aa.y + I12 * aa.z,
                I02 * aa.x + I12 * aa.y + I22 * aa.z} + cross(mc, al);
    V3 Ivl = m * vl + cross(va, mc);
    V3 Iva = V3{I00 * va.x + I01 * va.y + I02 * va.z,
                I01 * va.x + I11 * va.y + I12 * va.z,
                I02 * va.x + I12 * va.y + I22 * va.z} + cross(mc, vl);
    fl = Ial + cross(va, Ivl);
    fa = Iaa + cross(va, Iva) + cross(vl, Ivl);
}

template <int AX>
__device__ __forceinline__ float bwd_step(const float* __restrict__ C, float s, float c,
                                          V3 fl, V3 fa, V3& cl, V3& ca) {
    V3 tl = fl + cl;
    V3 ta = fa + ca;
    float tau;
    if (AX == 0) tau = ta.z;
    else if (AX == 1) tau = ta.y;
    else tau = -ta.y;

    V3 R0, R1, R2;
    make_R<AX>(C, s, c, R0, R1, R2);
    V3 p{C[9], C[10], C[11]};
    V3 nl = tl.x * R0 + tl.y * R1 + tl.z * R2;               // R @ tl (cols)
    V3 na = ta.x * R0 + ta.y * R1 + ta.z * R2 + cross(p, nl);
    cl = nl;
    ca = na;
    return tau;
}

// ---------- main kernel ----------
__global__ __launch_bounds__(BLK) void rnea_main(
    const float* __restrict__ q_g, const float* __restrict__ qd_g,
    const float* __restrict__ qdd_g, const float* __restrict__ cst,
    float* __restrict__ out, int n_elem) {
    __shared__ float sQ[STAGE], sQd[STAGE], sQdd[STAGE];
    const int t = threadIdx.x;
    const int base = blockIdx.x * STAGE;
#pragma unroll
    for (int i = t; i < STAGE; i += BLK) {
        const int g = base + i;
        const bool ok = g < n_elem;
        sQ[i] = ok ? q_g[g] : 0.f;
        sQd[i] = ok ? qd_g[g] : 0.f;
        sQdd[i] = ok ? qdd_g[g] : 0.f;
    }
    __syncthreads();

    const int o = t * NDOF;
    V3 vl{0.f, 0.f, 0.f}, va{0.f, 0.f, 0.f}, al{0.f, 0.f, 9.81f}, aa{0.f, 0.f, 0.f};
    float ss[NDOF], cc[NDOF];
    V3 fl[NDOF], fa[NDOF];

    // axis sequence: z, y, z, -y, z, y, z
    fwd_step<0>(cst + 0 * CST_STRIDE, sQ[o + 0], sQd[o + 0], sQdd[o + 0], vl, va, al, aa, ss[0], cc[0], fl[0], fa[0]);
    fwd_step<1>(cst + 1 * CST_STRIDE, sQ[o + 1], sQd[o + 1], sQdd[o + 1], vl, va, al, aa, ss[1], cc[1], fl[1], fa[1]);
    fwd_step<0>(cst + 2 * CST_STRIDE, sQ[o + 2], sQd[o + 2], sQdd[o + 2], vl, va, al, aa, ss[2], cc[2], fl[2], fa[2]);
    fwd_step<2>(cst + 3 * CST_STRIDE, sQ[o + 3], sQd[o + 3], sQdd[o + 3], vl, va, al, aa, ss[3], cc[3], fl[3], fa[3]);
    fwd_step<0>(cst + 4 * CST_STRIDE, sQ[o + 4], sQd[o + 4], sQdd[o + 4], vl, va, al, aa, ss[4], cc[4], fl[4], fa[4]);
    fwd_step<1>(cst + 5 * CST_STRIDE, sQ[o + 5], sQd[o + 5], sQdd[o + 5], vl, va, al, aa, ss[5], cc[5], fl[5], fa[5]);
    fwd_step<0>(cst + 6 * CST_STRIDE, sQ[o + 6], sQd[o + 6], sQdd[o + 6], vl, va, al, aa, ss[6], cc[6], fl[6], fa[6]);

    V3 cl{0.f, 0.f, 0.f}, ca{0.f, 0.f, 0.f};
    float tau[NDOF];
    tau[6] = bwd_step<0>(cst + 6 * CST_STRIDE, ss[6], cc[6], fl[6], fa[6], cl, ca);
    tau[5] = bwd_step<1>(cst + 5 * CST_STRIDE, ss[5], cc[5], fl[5], fa[5], cl, ca);
    tau[4] = bwd_step<0>(cst + 4 * CST_STRIDE, ss[4], cc[4], fl[4], fa[4], cl, ca);
    tau[3] = bwd_step<2>(cst + 3 * CST_STRIDE, ss[3], cc[3], fl[3], fa[3], cl, ca);
    tau[2] = bwd_step<0>(cst + 2 * CST_STRIDE, ss[2], cc[2], fl[2], fa[2], cl, ca);
    tau[1] = bwd_step<1>(cst + 1 * CST_STRIDE, ss[1], cc[1], fl[1], fa[1], cl, ca);
    tau[0] = bwd_step<0>(cst + 0 * CST_STRIDE, ss[0], cc[0], fl[0], fa[0], cl, ca);

    __syncthreads();
#pragma unroll
    for (int d = 0; d < NDOF; d++)
        sQ[o + d] = tau[d] + cst[d * CST_STRIDE + 22] * sQd[o + d];
    __syncthreads();
#pragma unroll
    for (int i = t; i < STAGE; i += BLK) {
        const int g = base + i;
        if (g < n_elem) out[g] = sQ[i];
    }
}

extern "C" void kernel_launch(void* const* d_in, const int* in_sizes, int n_in,
                              void* d_out, int out_size, void* d_ws, size_t ws_size,
                              hipStream_t stream) {
    const float* q = (const float*)d_in[0];
    const float* qd = (const float*)d_in[1];
    const float* qdd = (const float*)d_in[2];
    const float* rot_fix = (const float*)d_in[3];
    const float* trans_fix = (const float*)d_in[4];
    // d_in[5] = joint_axes: compile-time constant in the reference (z,y,z,-y,z,y,z)
    const float* mass = (const float*)d_in[6];
    const float* com = (const float*)d_in[7];
    const float* inertia = (const float*)d_in[8];
    const float* damping = (const float*)d_in[9];
    float* out = (float*)d_out;
    float* cst = (float*)d_ws;  // 7*24*4 = 672 B

    const int n_elem = in_sizes[0];  // B * 7
    const int B = n_elem / NDOF;
    const int grid = (B + BLK - 1) / BLK;

    rnea_prep<<<1, 64, 0, stream>>>(rot_fix, trans_fix, mass, com, inertia, damping, cst);
    rnea_main<<<grid, BLK, 0, stream>>>(q, qd, qdd, cst, out, n_elem);
}

// Round 4
// 152.513 us; speedup vs baseline: 1.3739x; 1.0511x over previous
//
#include <hip/hip_runtime.h>

#define NDOF 7
#define BLK 256
#define STAGE (BLK * NDOF)
#define CST_STRIDE 24   // floats per dof block (96 B, keeps 16B alignment for s_load_dwordx4)

// Wave-uniform constants land here; reads compile to s_load_* (scalar K$ path).
// prep kernel writes it through a generic pointer (hipGetSymbolAddress); the
// dispatch-boundary release makes it coherent for the next kernel.
__constant__ float g_cst[NDOF * CST_STRIDE];

// ---------- tiny vec3 ----------
struct V3 { float x, y, z; };
__device__ __forceinline__ V3 operator+(V3 a, V3 b) { return {a.x + b.x, a.y + b.y, a.z + b.z}; }
__device__ __forceinline__ V3 operator-(V3 a, V3 b) { return {a.x - b.x, a.y - b.y, a.z - b.z}; }
__device__ __forceinline__ V3 operator*(float s, V3 a) { return {s * a.x, s * a.y, s * a.z}; }
__device__ __forceinline__ V3 cross(V3 a, V3 b) {
    return {a.y * b.z - a.z * b.y, a.z * b.x - a.x * b.z, a.x * b.y - a.y * b.x};
}
__device__ __forceinline__ float dot(V3 a, V3 b) { return a.x * b.x + a.y * b.y + a.z * b.z; }

// ---------- prep: pack per-dof constants ----------
// layout per dof d (stride 24 floats):
//  [0:9)  F columns: Fc0=(F00,F10,F20), Fc1, Fc2
//  [9:12) p = trans_fix[1+d]
//  [12:18) Io6 = I00,I01,I02,I11,I12,I22  (inertia + m*(|c|^2 I - c c^T))
//  [18]   m
//  [19:22) mc = m*com
//  [22]   damping
__global__ void rnea_prep(const float* __restrict__ rot_fix,
                          const float* __restrict__ trans_fix,
                          const float* __restrict__ mass_g,
                          const float* __restrict__ com_g,
                          const float* __restrict__ inertia_g,
                          const float* __restrict__ damping_g,
                          float* __restrict__ cst) {
    const int d = threadIdx.x;
    if (d >= NDOF) return;
    float* o = cst + d * CST_STRIDE;
    const float* F = rot_fix + (1 + d) * 9;
#pragma unroll
    for (int j = 0; j < 3; j++)
#pragma unroll
        for (int i = 0; i < 3; i++) o[j * 3 + i] = F[i * 3 + j];  // column-major
#pragma unroll
    for (int i = 0; i < 3; i++) o[9 + i] = trans_fix[(1 + d) * 3 + i];
    const float m = mass_g[1 + d];
    const float c0 = com_g[(1 + d) * 3 + 0];
    const float c1 = com_g[(1 + d) * 3 + 1];
    const float c2 = com_g[(1 + d) * 3 + 2];
    const float* I = inertia_g + (1 + d) * 9;
    o[12] = I[0] + m * (c1 * c1 + c2 * c2);
    o[13] = I[1] - m * c0 * c1;
    o[14] = I[2] - m * c0 * c2;
    o[15] = I[4] + m * (c0 * c0 + c2 * c2);
    o[16] = I[5] - m * c1 * c2;
    o[17] = I[8] + m * (c0 * c0 + c1 * c1);
    o[18] = m;
    o[19] = m * c0;
    o[20] = m * c1;
    o[21] = m * c2;
    o[22] = damping_g[d];
    o[23] = 0.f;
}

// ---------- per-dof steps; D and AX are compile-time ----------
// AX: 0 = +z, 1 = +y, 2 = -y   (joint_axes is a literal in the reference)
template <int D, int AX>
__device__ __forceinline__ void make_R(float s, float c, V3& R0, V3& R1, V3& R2) {
    const float* C = g_cst + D * CST_STRIDE;
    V3 Fc0{C[0], C[1], C[2]}, Fc1{C[3], C[4], C[5]}, Fc2{C[6], C[7], C[8]};
    if (AX == 0) {          // Rq_z cols: (c,s,0), (-s,c,0), (0,0,1)
        R0 = c * Fc0 + s * Fc1;
        R1 = c * Fc1 - s * Fc0;
        R2 = Fc2;
    } else if (AX == 1) {   // Rq_y cols: (c,0,-s), (0,1,0), (s,0,c)
        R0 = c * Fc0 - s * Fc2;
        R1 = Fc1;
        R2 = s * Fc0 + c * Fc2;
    } else {                // Rq_-y cols: (c,0,s), (0,1,0), (-s,0,c)
        R0 = c * Fc0 + s * Fc2;
        R1 = Fc1;
        R2 = c * Fc2 - s * Fc0;
    }
}

template <int D, int AX>
__device__ __forceinline__ void fwd_step(float q, float qd, float qdd, V3& vl, V3& va,
                                         V3& al, V3& aa, float& s_sv, float& c_sv,
                                         V3& fl, V3& fa) {
    const float* C = g_cst + D * CST_STRIDE;
    // __sinf/__cosf only — pointer-form __sincosf escapes an addrspace(5) ptr,
    // defeats SROA, and spilled ~690 B/thread to scratch in round 2.
    const float s = __sinf(q);
    const float c = __cosf(q);
    s_sv = s;
    c_sv = c;
    V3 R0, R1, R2;
    make_R<D, AX>(s, c, R0, R1, R2);
    V3 p{C[9], C[10], C[11]};

    // Rt(vl) + cross(-Rt p, Rt va) == Rt(vl + va x p)
    V3 w1 = vl + cross(va, p);
    V3 w2 = al + cross(aa, p);
    V3 nvl{dot(R0, w1), dot(R1, w1), dot(R2, w1)};
    V3 nva{dot(R0, va), dot(R1, va), dot(R2, va)};
    V3 nal{dot(R0, w2), dot(R1, w2), dot(R2, w2)};
    V3 naa{dot(R0, aa), dot(R1, aa), dot(R2, aa)};

    if (AX == 0) {          // jv=(0,0,qd): cross(v,jv)=(v.y*qd,-v.x*qd,0)
        va = {nva.x, nva.y, nva.z + qd};
        aa = {naa.x + va.y * qd, naa.y - va.x * qd, naa.z + qdd};
        vl = nvl;
        al = {nal.x + vl.y * qd, nal.y - vl.x * qd, nal.z};
    } else if (AX == 1) {   // jv=(0,qd,0): cross(v,jv)=(-v.z*qd,0,v.x*qd)
        va = {nva.x, nva.y + qd, nva.z};
        aa = {naa.x - va.z * qd, naa.y + qdd, naa.z + va.x * qd};
        vl = nvl;
        al = {nal.x - vl.z * qd, nal.y, nal.z + vl.x * qd};
    } else {                // jv=(0,-qd,0): cross(v,jv)=(v.z*qd,0,-v.x*qd)
        va = {nva.x, nva.y - qd, nva.z};
        aa = {naa.x + va.z * qd, naa.y - qdd, naa.z - va.x * qd};
        vl = nvl;
        al = {nal.x + vl.z * qd, nal.y, nal.z - vl.x * qd};
    }

    const float I00 = C[12], I01 = C[13], I02 = C[14], I11 = C[15], I12 = C[16], I22 = C[17];
    const float m = C[18];
    V3 mc{C[19], C[20], C[21]};
    V3 Ial = m * al + cross(aa, mc);
    V3 Iaa = V3{I00 * aa.x + I01 * aa.y + I02 * aa.z,
                I01 * aa.x + I11 * aa.y + I12 * aa.z,
                I02 * aa.x + I12 * aa.y + I22 * aa.z} + cross(mc, al);
    V3 Ivl = m * vl + cross(va, mc);
    V3 Iva = V3{I00 * va.x + I01 * va.y + I02 * va.z,
                I01 * va.x + I11 * va.y + I12 * va.z,
                I02 * va.x + I12 * va.y + I22 * va.z} + cross(mc, vl);
    fl = Ial + cross(va, Ivl);
    fa = Iaa + cross(va, Iva) + cross(vl, Ivl);
}

template <int D, int AX>
__device__ __forceinline__ float bwd_step(float s, float c, V3 fl, V3 fa, V3& cl, V3& ca) {
    const float* C = g_cst + D * CST_STRIDE;
    V3 tl = fl + cl;
    V3 ta = fa + ca;
    float tau;
    if (AX == 0) tau = ta.z;
    else if (AX == 1) tau = ta.y;
    else tau = -ta.y;

    V3 R0, R1, R2;
    make_R<D, AX>(s, c, R0, R1, R2);
    V3 p{C[9], C[10], C[11]};
    V3 nl = tl.x * R0 + tl.y * R1 + tl.z * R2;   // R @ tl (columns)
    V3 na = ta.x * R0 + ta.y * R1 + ta.z * R2 + cross(p, nl);
    cl = nl;
    ca = na;
    return tau;
}

// ---------- main kernel ----------
__global__ __launch_bounds__(BLK) void rnea_main(
    const float* __restrict__ q_g, const float* __restrict__ qd_g,
    const float* __restrict__ qdd_g, float* __restrict__ out, int n_elem) {
    __shared__ float sQ[STAGE], sQd[STAGE], sQdd[STAGE];
    const int t = threadIdx.x;
    const int base = blockIdx.x * STAGE;
    if (base + STAGE <= n_elem) {
#pragma unroll
        for (int i = t; i < STAGE; i += BLK) {
            const int g = base + i;
            sQ[i] = q_g[g];
            sQd[i] = qd_g[g];
            sQdd[i] = qdd_g[g];
        }
    } else {
#pragma unroll
        for (int i = t; i < STAGE; i += BLK) {
            const int g = base + i;
            const bool ok = g < n_elem;
            sQ[i] = ok ? q_g[g] : 0.f;
            sQd[i] = ok ? qd_g[g] : 0.f;
            sQdd[i] = ok ? qdd_g[g] : 0.f;
        }
    }
    __syncthreads();

    const int o = t * NDOF;
    V3 vl{0.f, 0.f, 0.f}, va{0.f, 0.f, 0.f}, al{0.f, 0.f, 9.81f}, aa{0.f, 0.f, 0.f};
    float ss[NDOF], cc[NDOF];
    V3 fl[NDOF], fa[NDOF];

    // axis sequence: z, y, z, -y, z, y, z
    fwd_step<0, 0>(sQ[o + 0], sQd[o + 0], sQdd[o + 0], vl, va, al, aa, ss[0], cc[0], fl[0], fa[0]);
    fwd_step<1, 1>(sQ[o + 1], sQd[o + 1], sQdd[o + 1], vl, va, al, aa, ss[1], cc[1], fl[1], fa[1]);
    fwd_step<2, 0>(sQ[o + 2], sQd[o + 2], sQdd[o + 2], vl, va, al, aa, ss[2], cc[2], fl[2], fa[2]);
    fwd_step<3, 2>(sQ[o + 3], sQd[o + 3], sQdd[o + 3], vl, va, al, aa, ss[3], cc[3], fl[3], fa[3]);
    fwd_step<4, 0>(sQ[o + 4], sQd[o + 4], sQdd[o + 4], vl, va, al, aa, ss[4], cc[4], fl[4], fa[4]);
    fwd_step<5, 1>(sQ[o + 5], sQd[o + 5], sQdd[o + 5], vl, va, al, aa, ss[5], cc[5], fl[5], fa[5]);
    fwd_step<6, 0>(sQ[o + 6], sQd[o + 6], sQdd[o + 6], vl, va, al, aa, ss[6], cc[6], fl[6], fa[6]);

    V3 cl{0.f, 0.f, 0.f}, ca{0.f, 0.f, 0.f};
    float tau[NDOF];
    tau[6] = bwd_step<6, 0>(ss[6], cc[6], fl[6], fa[6], cl, ca);
    tau[5] = bwd_step<5, 1>(ss[5], cc[5], fl[5], fa[5], cl, ca);
    tau[4] = bwd_step<4, 0>(ss[4], cc[4], fl[4], fa[4], cl, ca);
    tau[3] = bwd_step<3, 2>(ss[3], cc[3], fl[3], fa[3], cl, ca);
    tau[2] = bwd_step<2, 0>(ss[2], cc[2], fl[2], fa[2], cl, ca);
    tau[1] = bwd_step<1, 1>(ss[1], cc[1], fl[1], fa[1], cl, ca);
    tau[0] = bwd_step<0, 0>(ss[0], cc[0], fl[0], fa[0], cl, ca);

    __syncthreads();
#pragma unroll
    for (int d = 0; d < NDOF; d++)
        sQ[o + d] = tau[d] + g_cst[d * CST_STRIDE + 22] * sQd[o + d];
    __syncthreads();
#pragma unroll
    for (int i = t; i < STAGE; i += BLK) {
        const int g = base + i;
        if (g < n_elem) out[g] = sQ[i];
    }
}

extern "C" void kernel_launch(void* const* d_in, const int* in_sizes, int n_in,
                              void* d_out, int out_size, void* d_ws, size_t ws_size,
                              hipStream_t stream) {
    const float* q = (const float*)d_in[0];
    const float* qd = (const float*)d_in[1];
    const float* qdd = (const float*)d_in[2];
    const float* rot_fix = (const float*)d_in[3];
    const float* trans_fix = (const float*)d_in[4];
    // d_in[5] = joint_axes: compile-time constant in the reference (z,y,z,-y,z,y,z)
    const float* mass = (const float*)d_in[6];
    const float* com = (const float*)d_in[7];
    const float* inertia = (const float*)d_in[8];
    const float* damping = (const float*)d_in[9];
    float* out = (float*)d_out;

    void* sym = nullptr;
    hipGetSymbolAddress(&sym, HIP_SYMBOL(g_cst));  // pure lookup, capture-safe

    const int n_elem = in_sizes[0];  // B * 7
    const int B = n_elem / NDOF;
    const int grid = (B + BLK - 1) / BLK;

    rnea_prep<<<1, 64, 0, stream>>>(rot_fix, trans_fix, mass, com, inertia, damping,
                                    (float*)sym);
    rnea_main<<<grid, BLK, 0, stream>>>(q, qd, qdd, out, n_elem);
}